// Round 12
// baseline (208.334 us; speedup 1.0000x reference)
//
#include <hip/hip_runtime.h>
#include <hip/hip_bf16.h>
#include <math.h>

// B=4, NB=2048 -> 8192 leaf blocks of L=16 tokens x C=128; H=8 heads x D=16.
// 512 threads (8 waves), NITER=4 blocks/WG, 2 barriers/iter, single-bf16 path.
// Weight tiles q/k/v/proj are REGISTER-RESIDENT (loaded once per WG); only the
// tiny gate tile is re-loaded per iteration (L2-hot, hidden under the MLP).
typedef __attribute__((ext_vector_type(8))) short bf16x8;
typedef __attribute__((ext_vector_type(4))) float f32x4;
typedef __attribute__((ext_vector_type(4))) unsigned short us4;
typedef __attribute__((ext_vector_type(2))) unsigned int u32x2;

#define NITER 4

static __device__ __forceinline__ unsigned short f2bf_rn(float f) {
    union { __hip_bfloat16 h; unsigned short u; } cv;
    cv.h = __float2bfloat16(f);
    return cv.u;
}
static __device__ __forceinline__ float bf2f(unsigned short u) {
    union { unsigned int i; float f; } cv;
    cv.i = ((unsigned int)u) << 16;
    return cv.f;
}
static __device__ __forceinline__ f32x4 MFMA(bf16x8 a, bf16x8 b, f32x4 c) {
    return __builtin_amdgcn_mfma_f32_16x16x32_bf16(a, b, c, 0, 0, 0);
}
static __device__ __forceinline__ float sigmoid_fast(float t) {
    return __builtin_amdgcn_rcpf(1.f + __expf(-t));
}

// ---- prep: Wbig = bf16([Wqkv(384); Wbr(8); zeros(8)]) [400][128]; Wp = bf16(Wproj)
__global__ __launch_bounds__(256) void prep_kernel(
    const float* __restrict__ Wqkv, const float* __restrict__ Wbr,
    const float* __restrict__ Wproj,
    unsigned short* __restrict__ Wbig, unsigned short* __restrict__ Wp)
{
    int i = blockIdx.x * 256 + threadIdx.x;
    if (i < 400 * 128) {
        int n = i >> 7, k = i & 127;
        float v = (n < 384) ? Wqkv[i] : (n < 392 ? Wbr[(n - 384) * 128 + k] : 0.f);
        Wbig[i] = f2bf_rn(v);
    } else {
        int j = i - 400 * 128;
        if (j < 128 * 128) Wp[j] = f2bf_rn(Wproj[j]);
    }
}

__global__ __launch_bounds__(512, 4) void leaf_main(
    const float* __restrict__ x, const int* __restrict__ mask,
    const float* __restrict__ edge,
    const unsigned short* __restrict__ Wbig, const unsigned short* __restrict__ Wp,
    const float* __restrict__ bqkv, const float* __restrict__ bproj,
    const float* __restrict__ eg_w1, const float* __restrict__ eg_b1,
    const float* __restrict__ eg_w2, const float* __restrict__ eg_b2,
    const float* __restrict__ bbr, float* __restrict__ out)
{
    __shared__ unsigned short qhiS[16 * 136];                  // q rounded bf16
    __shared__ unsigned short khiS[16 * 136];                  // k rounded bf16
    __shared__ unsigned short vtS[128 * 24];                   // [h*16+d][tok(24)]
    __shared__ unsigned short ewS[8 * 256];                    // [h][q*16+k]
    __shared__ float logitS[256];                              // [q*16+k]
    __shared__ unsigned short pS[8 * 16 * 24];                 // per-wave P
    __shared__ unsigned short mhiS[16 * 136];                  // x_mid rounded
    __shared__ unsigned short xhiS[16 * 128];                  // x stage (bf16)
    // total ~34.6 KB

    const int tid  = threadIdx.x;
    const int lane = tid & 63;
    const int wave = tid >> 6;
    const int c15  = lane & 15;
    const int quad = lane >> 4;
    const bf16x8 zf = {0, 0, 0, 0, 0, 0, 0, 0};
    const int bid0 = blockIdx.x * NITER;

    // iteration-invariant scalars
    const float bq0 = bqkv[wave * 16 + c15];
    const float bq1 = bqkv[128 + wave * 16 + c15];
    const float bq2 = bqkv[256 + wave * 16 + c15];
    const float bgate = bbr[c15 & 7];
    const float bpv = bproj[wave * 16 + c15];

    // ---- REGISTER-RESIDENT weight tiles (loaded once per WG) ----
    bf16x8 Bq[4], Bk[4], Bv[4], Wt[4];
    {
        const unsigned short* wq = Wbig + (wave * 16 + c15) * 128 + quad * 8;
        const unsigned short* wk = Wbig + ((8 + wave) * 16 + c15) * 128 + quad * 8;
        const unsigned short* wv = Wbig + ((16 + wave) * 16 + c15) * 128 + quad * 8;
        const unsigned short* wp = Wp + (wave * 16 + c15) * 128 + quad * 8;
        #pragma unroll
        for (int kk = 0; kk < 4; ++kk) {
            Bq[kk] = *(const bf16x8*)(wq + kk * 32);
            Bk[kk] = *(const bf16x8*)(wk + kk * 32);
            Bv[kk] = *(const bf16x8*)(wv + kk * 32);
            Wt[kk] = *(const bf16x8*)(wp + kk * 32);
        }
    }
    const unsigned short* wg = Wbig + (384 + c15) * 128 + quad * 8;  // gate tile base

    // ---- prologue: block 0 inputs ----
    int mv = 0;
    float4 evv = make_float4(0.f, 0.f, 0.f, 0.f);
    if (tid < 256) {
        mv  = mask[(size_t)bid0 * 256 + tid];
        evv = *(const float4*)&edge[((size_t)bid0 * 256 + tid) * 4];
    }
    float4 xv = ((const float4*)(x + (size_t)bid0 * 2048))[tid];

    // stage x block 0 (rounded bf16, chunk-XOR swizzle)
    {
        int row = tid >> 5, c4 = tid & 31;
        int off = row * 128 + (((c4 >> 1) ^ (row & 7)) << 3) + ((c4 & 1) << 2);
        us4 hi;
        hi[0] = f2bf_rn(xv.x); hi[1] = f2bf_rn(xv.y);
        hi[2] = f2bf_rn(xv.z); hi[3] = f2bf_rn(xv.w);
        *(us4*)&xhiS[off] = hi;
    }
    __syncthreads();   // prologue barrier: x0 staged

    #pragma unroll 1
    for (int it = 0; it < NITER; ++it) {
        const int bid = bid0 + it;
        const bool more = (it + 1 < NITER);

        // gate tile load (L2-hot; retires under the MLP)
        bf16x8 Bg[4];
        #pragma unroll
        for (int kk = 0; kk < 4; ++kk) Bg[kk] = *(const bf16x8*)(wg + kk * 32);

        // next-block loads (retire under this iteration's compute)
        float4 xv_n = make_float4(0.f, 0.f, 0.f, 0.f);
        int mv_n = 0;
        float4 ev_n = make_float4(0.f, 0.f, 0.f, 0.f);
        if (more) {
            xv_n = ((const float4*)(x + (size_t)(bid + 1) * 2048))[tid];
            if (tid < 256) {
                mv_n = mask[(size_t)(bid + 1) * 256 + tid];
                ev_n = *(const float4*)&edge[((size_t)(bid + 1) * 256 + tid) * 4];
            }
        }

        // ---- edge-gate MLP (poly gelu) + mask/logits (waves 0-3) ----
        if (tid < 256) {
            const int q = tid >> 4, k = tid & 15;
            int s = mv;
            s += __shfl_xor(s, 1); s += __shfl_xor(s, 2);
            s += __shfl_xor(s, 4); s += __shfl_xor(s, 8);
            float m = (float)mv;
            if (q == k && s < 1) m = 1.f;
            float bp0, bp1, bp2, bp3;
            if (q == k) { bp0 = bp1 = bp2 = 0.f; bp3 = 1.f; }
            else        { bp0 = evv.x; bp1 = evv.y; bp2 = evv.z; bp3 = evv.w; }
            logitS[tid] = (m == 0.f) ? -INFINITY : bp3;
            float ew[8];
            #pragma unroll
            for (int h = 0; h < 8; ++h) ew[h] = eg_b2[h];
            #pragma unroll
            for (int j = 0; j < 16; ++j) {
                float z = eg_w1[j * 4 + 0] * bp0 + eg_w1[j * 4 + 1] * bp1 +
                          eg_w1[j * 4 + 2] * bp2 + eg_w1[j * 4 + 3] * bp3 + eg_b1[j];
                float u = z * z;
                float w = __builtin_fmaf(-0.0664904f, u, 0.3989423f);
                float g = z * __builtin_fmaf(z, w, 0.5f);
                #pragma unroll
                for (int h = 0; h < 8; ++h) ew[h] = __builtin_fmaf(eg_w2[h * 16 + j], g, ew[h]);
            }
            #pragma unroll
            for (int h = 0; h < 8; ++h)
                ewS[h * 256 + tid] = (m == 0.f) ? (unsigned short)0
                                   : (unsigned short)(__float_as_uint(ew[h]) >> 16);
        }

        // ---- A-fragments from LDS ----
        bf16x8 ah[4];
        #pragma unroll
        for (int kk = 0; kk < 4; ++kk) {
            int off = c15 * 128 + (((kk * 4 + quad) ^ (c15 & 7)) << 3);
            ah[kk] = *(const bf16x8*)&xhiS[off];
        }

        const int colq = wave * 16 + c15;
        float vblk;
        float greg[4];

        // ---- tile q ----
        {
            f32x4 acc = {0.f, 0.f, 0.f, 0.f};
            #pragma unroll
            for (int kk = 0; kk < 4; ++kk) acc = MFMA(ah[kk], Bq[kk], acc);
            #pragma unroll
            for (int r = 0; r < 4; ++r)
                qhiS[(quad * 4 + r) * 136 + colq] = f2bf_rn(acc[r] + bq0);
        }

        // ---- tile k ----
        {
            f32x4 acc = {0.f, 0.f, 0.f, 0.f};
            #pragma unroll
            for (int kk = 0; kk < 4; ++kk) acc = MFMA(ah[kk], Bk[kk], acc);
            #pragma unroll
            for (int r = 0; r < 4; ++r)
                khiS[(quad * 4 + r) * 136 + colq] = f2bf_rn(acc[r] + bq1);
        }

        // ---- tile v (transposed; v_blk in-register) ----
        {
            f32x4 acc = {0.f, 0.f, 0.f, 0.f};
            #pragma unroll
            for (int kk = 0; kk < 4; ++kk) acc = MFMA(ah[kk], Bv[kk], acc);
            us4 vw;
            #pragma unroll
            for (int r = 0; r < 4; ++r) vw[r] = f2bf_rn(acc[r] + bq2);
            *(us4*)&vtS[colq * 24 + quad * 4] = vw;
            float s = acc[0] + acc[1] + acc[2] + acc[3];
            s += __shfl_xor(s, 16);
            s += __shfl_xor(s, 32);
            vblk = s * 0.0625f + bq2;     // per-lane = v_blk[wave*16+c15]
        }

        // ---- tile gate (every wave; keep own column via shuffle) ----
        {
            f32x4 acc = {0.f, 0.f, 0.f, 0.f};
            #pragma unroll
            for (int kk = 0; kk < 4; ++kk) acc = MFMA(ah[kk], Bg[kk], acc);
            const int src = (lane & 48) | wave;
            #pragma unroll
            for (int r = 0; r < 4; ++r) {
                float sg = sigmoid_fast(acc[r] + bgate);
                greg[r] = __shfl(sg, src);        // g[tok=quad*4+r][h=wave]
            }
        }
        __syncthreads();   // barrier B: qkv/MLP visible; x-stage reads done

        // stage NEXT block's x (overlaps attention; visibility via barrier C)
        if (more) {
            int row = tid >> 5, c4 = tid & 31;
            int off = row * 128 + (((c4 >> 1) ^ (row & 7)) << 3) + ((c4 & 1) << 2);
            us4 hi;
            hi[0] = f2bf_rn(xv_n.x); hi[1] = f2bf_rn(xv_n.y);
            hi[2] = f2bf_rn(xv_n.z); hi[3] = f2bf_rn(xv_n.w);
            *(us4*)&xhiS[off] = hi;
        }

        // ---- attention, swapped QK^T (head h = wave) ----
        {
            const int h = wave;
            const int fo = c15 * 136 + h * 16 + (quad & 1) * 8;
            bf16x8 kh_ = zf, qh_ = zf;
            if (quad < 2) {
                kh_ = *(const bf16x8*)&khiS[fo];
                qh_ = *(const bf16x8*)&qhiS[fo];
            }
            f32x4 sc = {0.f, 0.f, 0.f, 0.f};
            sc = MFMA(kh_, qh_, sc);
            const f32x4 lg = *(const f32x4*)&logitS[c15 * 16 + quad * 4];
            const us4 ew4 = *(const us4*)&ewS[h * 256 + c15 * 16 + quad * 4];
            float s0 = sc[0] * 0.25f + lg[0];
            float s1 = sc[1] * 0.25f + lg[1];
            float s2 = sc[2] * 0.25f + lg[2];
            float s3 = sc[3] * 0.25f + lg[3];
            float mx = fmaxf(fmaxf(s0, s1), fmaxf(s2, s3));
            mx = fmaxf(mx, __shfl_xor(mx, 16));
            mx = fmaxf(mx, __shfl_xor(mx, 32));
            float e0 = __expf(s0 - mx), e1 = __expf(s1 - mx);
            float e2 = __expf(s2 - mx), e3 = __expf(s3 - mx);
            float sm = (e0 + e1) + (e2 + e3);
            sm += __shfl_xor(sm, 16);
            sm += __shfl_xor(sm, 32);
            const float inv = __builtin_amdgcn_rcpf(sm);
            const float p0 = e0 * inv + bf2f(ew4[0]);
            const float p1 = e1 * inv + bf2f(ew4[1]);
            const float p2 = e2 * inv + bf2f(ew4[2]);
            const float p3 = e3 * inv + bf2f(ew4[3]);
            u32x2 pw;
            pw[0] = (unsigned int)f2bf_rn(p0) | ((unsigned int)f2bf_rn(p1) << 16);
            pw[1] = (unsigned int)f2bf_rn(p2) | ((unsigned int)f2bf_rn(p3) << 16);
            *(u32x2*)&pS[wave * 384 + c15 * 24 + quad * 4] = pw;

            bf16x8 pa = zf, vb = zf;
            if (quad < 2) {
                pa = *(const bf16x8*)&pS[wave * 384 + c15 * 24 + (quad & 1) * 8];
                vb = *(const bf16x8*)&vtS[(h * 16 + c15) * 24 + (quad & 1) * 8];
            }
            f32x4 xs = {0.f, 0.f, 0.f, 0.f};
            xs = MFMA(pa, vb, xs);
            #pragma unroll
            for (int r = 0; r < 4; ++r) {
                const int tok = quad * 4 + r;
                float val = xs[r] + greg[r] * vblk;
                mhiS[tok * 136 + h * 16 + c15] = f2bf_rn(val);
            }
        }
        __syncthreads();   // barrier C: x_mid + next-x staged visible

        // ---- output projection (resident Wt) ----
        {
            bf16x8 mh[4];
            #pragma unroll
            for (int kk = 0; kk < 4; ++kk)
                mh[kk] = *(const bf16x8*)&mhiS[c15 * 136 + kk * 32 + quad * 8];
            f32x4 acc = {0.f, 0.f, 0.f, 0.f};
            #pragma unroll
            for (int kk = 0; kk < 4; ++kk) acc = MFMA(mh[kk], Wt[kk], acc);
            float* op = out + (size_t)bid * 2048;
            #pragma unroll
            for (int r = 0; r < 4; ++r)
                op[(quad * 4 + r) * 128 + wave * 16 + c15] = acc[r] + bpv;
        }

        mv = mv_n;
        evv = ev_n;
    }
}

extern "C" void kernel_launch(void* const* d_in, const int* in_sizes, int n_in,
                              void* d_out, int out_size, void* d_ws, size_t ws_size,
                              hipStream_t stream) {
    const float* x     = (const float*)d_in[0];
    const int*   amask = (const int*)  d_in[1];
    const float* edge  = (const float*)d_in[2];
    const float* Wqkv  = (const float*)d_in[3];
    const float* bqkv  = (const float*)d_in[4];
    const float* Wproj = (const float*)d_in[5];
    const float* bproj = (const float*)d_in[6];
    const float* eg_w1 = (const float*)d_in[7];
    const float* eg_b1 = (const float*)d_in[8];
    const float* eg_w2 = (const float*)d_in[9];
    const float* eg_b2 = (const float*)d_in[10];
    const float* Wbr   = (const float*)d_in[11];
    const float* bbr   = (const float*)d_in[12];
    float* outp = (float*)d_out;

    unsigned short* Wbig = (unsigned short*)d_ws;                      // 400*128 bf16
    unsigned short* Wp   = (unsigned short*)((char*)d_ws + 400 * 128 * 2);

    hipLaunchKernelGGL(prep_kernel, dim3(264), dim3(256), 0, stream,
                       Wqkv, Wbr, Wproj, Wbig, Wp);
    hipLaunchKernelGGL(leaf_main, dim3(8192 / NITER), dim3(512), 0, stream,
                       x, amask, edge, Wbig, Wp, bqkv, bproj,
                       eg_w1, eg_b1, eg_w2, eg_b2, bbr, outp);
}

// Round 13
// 129.955 us; speedup vs baseline: 1.6031x; 1.6031x over previous
//
#include <hip/hip_runtime.h>
#include <hip/hip_bf16.h>
#include <math.h>

// B=4, NB=2048 -> 8192 leaf blocks of L=16 tokens x C=128; H=8 heads x D=16.
// 512 threads (8 waves), NITER=4 blocks/WG, ONE barrier per iteration:
// the edge-MLP is software-pipelined one block ahead (double-buffered ewS/logitS),
// x-stage and x_mid are double-buffered, qkv/attention buffers are wave-private.
// Wt (proj weights) register-resident; q/k/v/gate tiles roll through 2 slots.
typedef __attribute__((ext_vector_type(8))) short bf16x8;
typedef __attribute__((ext_vector_type(4))) float f32x4;
typedef __attribute__((ext_vector_type(4))) unsigned short us4;
typedef __attribute__((ext_vector_type(2))) unsigned int u32x2;

#define NITER 4

static __device__ __forceinline__ unsigned short f2bf_rn(float f) {
    union { __hip_bfloat16 h; unsigned short u; } cv;
    cv.h = __float2bfloat16(f);
    return cv.u;
}
static __device__ __forceinline__ float bf2f(unsigned short u) {
    union { unsigned int i; float f; } cv;
    cv.i = ((unsigned int)u) << 16;
    return cv.f;
}
static __device__ __forceinline__ f32x4 MFMA(bf16x8 a, bf16x8 b, f32x4 c) {
    return __builtin_amdgcn_mfma_f32_16x16x32_bf16(a, b, c, 0, 0, 0);
}
static __device__ __forceinline__ float sigmoid_fast(float t) {
    return __builtin_amdgcn_rcpf(1.f + __expf(-t));
}

// edge-gate MLP for one 256-pair block (caller guards tid<256; waves 0-3 whole)
static __device__ __forceinline__ void edge_mlp(
    int tid, int mv, float4 ev,
    const float* __restrict__ eg_w1, const float* __restrict__ eg_b1,
    const float* __restrict__ eg_w2, const float* __restrict__ eg_b2,
    unsigned short* __restrict__ ewP, float* __restrict__ logitP)
{
    const int q = tid >> 4, k = tid & 15;
    int s = mv;
    s += __shfl_xor(s, 1); s += __shfl_xor(s, 2);
    s += __shfl_xor(s, 4); s += __shfl_xor(s, 8);
    float m = (float)mv;
    if (q == k && s < 1) m = 1.f;
    float bp0, bp1, bp2, bp3;
    if (q == k) { bp0 = bp1 = bp2 = 0.f; bp3 = 1.f; }
    else        { bp0 = ev.x; bp1 = ev.y; bp2 = ev.z; bp3 = ev.w; }
    logitP[tid] = (m == 0.f) ? -INFINITY : bp3;
    float ew[8];
    #pragma unroll
    for (int h = 0; h < 8; ++h) ew[h] = eg_b2[h];
    #pragma unroll
    for (int j = 0; j < 16; ++j) {
        float z = eg_w1[j * 4 + 0] * bp0 + eg_w1[j * 4 + 1] * bp1 +
                  eg_w1[j * 4 + 2] * bp2 + eg_w1[j * 4 + 3] * bp3 + eg_b1[j];
        // gelu(z)=z*Phi(z); Phi ~= 0.5 + 0.3989423 z - 0.0664904 z^3 (|z|<1)
        float u = z * z;
        float w = __builtin_fmaf(-0.0664904f, u, 0.3989423f);
        float g = z * __builtin_fmaf(z, w, 0.5f);
        #pragma unroll
        for (int h = 0; h < 8; ++h) ew[h] = __builtin_fmaf(eg_w2[h * 16 + j], g, ew[h]);
    }
    #pragma unroll
    for (int h = 0; h < 8; ++h)
        ewP[h * 256 + tid] = (m == 0.f) ? (unsigned short)0
                           : (unsigned short)(__float_as_uint(ew[h]) >> 16);
}

// ---- prep: Wbig = bf16([Wqkv(384); Wbr(8); zeros(8)]) [400][128]; Wp = bf16(Wproj)
__global__ __launch_bounds__(256) void prep_kernel(
    const float* __restrict__ Wqkv, const float* __restrict__ Wbr,
    const float* __restrict__ Wproj,
    unsigned short* __restrict__ Wbig, unsigned short* __restrict__ Wp)
{
    int i = blockIdx.x * 256 + threadIdx.x;
    if (i < 400 * 128) {
        int n = i >> 7, k = i & 127;
        float v = (n < 384) ? Wqkv[i] : (n < 392 ? Wbr[(n - 384) * 128 + k] : 0.f);
        Wbig[i] = f2bf_rn(v);
    } else {
        int j = i - 400 * 128;
        if (j < 128 * 128) Wp[j] = f2bf_rn(Wproj[j]);
    }
}

__global__ __launch_bounds__(512) void leaf_main(
    const float* __restrict__ x, const int* __restrict__ mask,
    const float* __restrict__ edge,
    const unsigned short* __restrict__ Wbig, const unsigned short* __restrict__ Wp,
    const float* __restrict__ bqkv, const float* __restrict__ bproj,
    const float* __restrict__ eg_w1, const float* __restrict__ eg_b1,
    const float* __restrict__ eg_w2, const float* __restrict__ eg_b2,
    const float* __restrict__ bbr, float* __restrict__ out)
{
    __shared__ unsigned short qS[16 * 136];          // q (wave-private cols)
    __shared__ unsigned short kS[16 * 136];          // k (wave-private cols)
    __shared__ unsigned short vtS[128 * 24];         // v^T (wave-private rows)
    __shared__ unsigned short pS[8 * 16 * 24];       // per-wave P scratch
    __shared__ unsigned short mhiS[2][16 * 136];     // x_mid, double-buffered
    __shared__ unsigned short ewS[2][8 * 256];       // MLP out, double-buffered
    __shared__ float logitS[2][256];                 // logits, double-buffered
    __shared__ unsigned short xS[2][16 * 128];       // x stage, double-buffered
    // total 48128 B

    const int tid  = threadIdx.x;
    const int lane = tid & 63;
    const int wave = tid >> 6;
    const int c15  = lane & 15;
    const int quad = lane >> 4;
    const bf16x8 zf = {0, 0, 0, 0, 0, 0, 0, 0};
    const int bid0 = blockIdx.x * NITER;

    // iteration-invariant scalars
    const float bq0 = bqkv[wave * 16 + c15];
    const float bq1 = bqkv[128 + wave * 16 + c15];
    const float bq2 = bqkv[256 + wave * 16 + c15];
    const float bgate = bbr[c15 & 7];
    const float bpv = bproj[wave * 16 + c15];

    // resident proj weights (loaded once; natural VGPR allocation, no bounds hint)
    bf16x8 Wt[4];
    {
        const unsigned short* wp = Wp + (wave * 16 + c15) * 128 + quad * 8;
        #pragma unroll
        for (int kk = 0; kk < 4; ++kk) Wt[kk] = *(const bf16x8*)(wp + kk * 32);
    }

    // rolling qkv/gate weight slots: entry invariant {slot0=q, slot1=k}
    bf16x8 Bt[2][4];
    const unsigned short* wbase = Wbig + c15 * 128 + quad * 8;
    {
        const unsigned short* w0 = wbase + (wave * 16) * 128;
        #pragma unroll
        for (int kk = 0; kk < 4; ++kk) Bt[0][kk] = *(const bf16x8*)(w0 + kk * 32);
        const unsigned short* w1 = wbase + ((8 + wave) * 16) * 128;
        #pragma unroll
        for (int kk = 0; kk < 4; ++kk) Bt[1][kk] = *(const bf16x8*)(w1 + kk * 32);
    }

    // prologue loads: block 0 (MLP now) + block 1 (MLP next iter, depth-2 hold)
    int mvP = 0, mvH = 0;
    float4 evP = make_float4(0.f, 0.f, 0.f, 0.f);
    float4 evH = make_float4(0.f, 0.f, 0.f, 0.f);
    if (tid < 256) {
        mvP = mask[(size_t)bid0 * 256 + tid];
        evP = *(const float4*)&edge[((size_t)bid0 * 256 + tid) * 4];
#if NITER > 1
        mvH = mask[(size_t)(bid0 + 1) * 256 + tid];
        evH = *(const float4*)&edge[((size_t)(bid0 + 1) * 256 + tid) * 4];
#endif
    }
    float4 xv0 = ((const float4*)(x + (size_t)bid0 * 2048))[tid];

    // stage x block 0 into xS[0] (rounded bf16, chunk-XOR swizzle)
    {
        int row = tid >> 5, c4 = tid & 31;
        int off = row * 128 + (((c4 >> 1) ^ (row & 7)) << 3) + ((c4 & 1) << 2);
        us4 hi;
        hi[0] = f2bf_rn(xv0.x); hi[1] = f2bf_rn(xv0.y);
        hi[2] = f2bf_rn(xv0.z); hi[3] = f2bf_rn(xv0.w);
        *(us4*)&xS[0][off] = hi;
    }
    // MLP for block 0 -> buffers parity 0
    if (tid < 256)
        edge_mlp(tid, mvP, evP, eg_w1, eg_b1, eg_w2, eg_b2, ewS[0], logitS[0]);
    __syncthreads();   // prologue barrier

    #pragma unroll 1
    for (int it = 0; it < NITER; ++it) {
        const int bid = bid0 + it;
        const int p = it & 1;
        const bool more = (it + 1 < NITER);

        // next-block x load (staged at end of this iter)
        float4 xv_n = make_float4(0.f, 0.f, 0.f, 0.f);
        if (more) xv_n = ((const float4*)(x + (size_t)(bid + 1) * 2048))[tid];
        // depth-2 mask/edge for block it+2 (consumed next iter's MLP)
        int mv_n = 0;
        float4 ev_n = make_float4(0.f, 0.f, 0.f, 0.f);
        if (it + 2 < NITER && tid < 256) {
            mv_n = mask[(size_t)(bid + 2) * 256 + tid];
            ev_n = *(const float4*)&edge[((size_t)(bid + 2) * 256 + tid) * 4];
        }

        // ---- MLP for block it+1 (writes parity p^1; consumed next iteration) ----
        if (more && tid < 256)
            edge_mlp(tid, mvH, evH, eg_w1, eg_b1, eg_w2, eg_b2, ewS[p ^ 1], logitS[p ^ 1]);

        // ---- A-fragments from xS[p] ----
        bf16x8 ah[4];
        #pragma unroll
        for (int kk = 0; kk < 4; ++kk) {
            int off = c15 * 128 + (((kk * 4 + quad) ^ (c15 & 7)) << 3);
            ah[kk] = *(const bf16x8*)&xS[p][off];
        }

        const int colq = wave * 16 + c15;
        float vblk;
        float greg[4];

        // ---- tile q (Bt[0]) ----
        {
            f32x4 acc = {0.f, 0.f, 0.f, 0.f};
            #pragma unroll
            for (int kk = 0; kk < 4; ++kk) acc = MFMA(ah[kk], Bt[0][kk], acc);
            const unsigned short* w2 = wbase + ((16 + wave) * 16) * 128;  // v-tile
            #pragma unroll
            for (int kk = 0; kk < 4; ++kk) Bt[0][kk] = *(const bf16x8*)(w2 + kk * 32);
            #pragma unroll
            for (int r = 0; r < 4; ++r)
                qS[(quad * 4 + r) * 136 + colq] = f2bf_rn(acc[r] + bq0);
        }

        // ---- tile k (Bt[1]) ----
        {
            f32x4 acc = {0.f, 0.f, 0.f, 0.f};
            #pragma unroll
            for (int kk = 0; kk < 4; ++kk) acc = MFMA(ah[kk], Bt[1][kk], acc);
            const unsigned short* w3 = wbase + 384 * 128;                 // gate tile
            #pragma unroll
            for (int kk = 0; kk < 4; ++kk) Bt[1][kk] = *(const bf16x8*)(w3 + kk * 32);
            #pragma unroll
            for (int r = 0; r < 4; ++r)
                kS[(quad * 4 + r) * 136 + colq] = f2bf_rn(acc[r] + bq1);
        }

        // ---- tile v (Bt[0]; v_blk in-register) ----
        {
            f32x4 acc = {0.f, 0.f, 0.f, 0.f};
            #pragma unroll
            for (int kk = 0; kk < 4; ++kk) acc = MFMA(ah[kk], Bt[0][kk], acc);
            const unsigned short* w0 = wbase + (wave * 16) * 128;         // next q
            #pragma unroll
            for (int kk = 0; kk < 4; ++kk) Bt[0][kk] = *(const bf16x8*)(w0 + kk * 32);
            us4 vw;
            #pragma unroll
            for (int r = 0; r < 4; ++r) vw[r] = f2bf_rn(acc[r] + bq2);
            *(us4*)&vtS[colq * 24 + quad * 4] = vw;
            float s = acc[0] + acc[1] + acc[2] + acc[3];
            s += __shfl_xor(s, 16);
            s += __shfl_xor(s, 32);
            vblk = s * 0.0625f + bq2;     // per-lane = v_blk[wave*16+c15]
        }

        // ---- tile gate (Bt[1]; own column via shuffle) ----
        {
            f32x4 acc = {0.f, 0.f, 0.f, 0.f};
            #pragma unroll
            for (int kk = 0; kk < 4; ++kk) acc = MFMA(ah[kk], Bt[1][kk], acc);
            const unsigned short* w1 = wbase + ((8 + wave) * 16) * 128;   // next k
            #pragma unroll
            for (int kk = 0; kk < 4; ++kk) Bt[1][kk] = *(const bf16x8*)(w1 + kk * 32);
            const int src = (lane & 48) | wave;
            #pragma unroll
            for (int r = 0; r < 4; ++r) {
                float sg = sigmoid_fast(acc[r] + bgate);
                greg[r] = __shfl(sg, src);        // g[tok=quad*4+r][h=wave]
            }
        }

        // ---- attention (NO barrier: wave-private qkv; ew/logit from parity p) ----
        {
            const int h = wave;
            const int fo = c15 * 136 + h * 16 + (quad & 1) * 8;
            bf16x8 kh_ = zf, qh_ = zf;
            if (quad < 2) {
                kh_ = *(const bf16x8*)&kS[fo];
                qh_ = *(const bf16x8*)&qS[fo];
            }
            f32x4 sc = {0.f, 0.f, 0.f, 0.f};
            sc = MFMA(kh_, qh_, sc);
            const f32x4 lg = *(const f32x4*)&logitS[p][c15 * 16 + quad * 4];
            const us4 ew4 = *(const us4*)&ewS[p][h * 256 + c15 * 16 + quad * 4];
            float s0 = sc[0] * 0.25f + lg[0];
            float s1 = sc[1] * 0.25f + lg[1];
            float s2 = sc[2] * 0.25f + lg[2];
            float s3 = sc[3] * 0.25f + lg[3];
            float mx = fmaxf(fmaxf(s0, s1), fmaxf(s2, s3));
            mx = fmaxf(mx, __shfl_xor(mx, 16));
            mx = fmaxf(mx, __shfl_xor(mx, 32));
            float e0 = __expf(s0 - mx), e1 = __expf(s1 - mx);
            float e2 = __expf(s2 - mx), e3 = __expf(s3 - mx);
            float sm = (e0 + e1) + (e2 + e3);
            sm += __shfl_xor(sm, 16);
            sm += __shfl_xor(sm, 32);
            const float inv = __builtin_amdgcn_rcpf(sm);
            const float p0 = e0 * inv + bf2f(ew4[0]);
            const float p1 = e1 * inv + bf2f(ew4[1]);
            const float p2 = e2 * inv + bf2f(ew4[2]);
            const float p3 = e3 * inv + bf2f(ew4[3]);
            u32x2 pw;
            pw[0] = (unsigned int)f2bf_rn(p0) | ((unsigned int)f2bf_rn(p1) << 16);
            pw[1] = (unsigned int)f2bf_rn(p2) | ((unsigned int)f2bf_rn(p3) << 16);
            *(u32x2*)&pS[wave * 384 + c15 * 24 + quad * 4] = pw;

            bf16x8 pa = zf, vb = zf;
            if (quad < 2) {
                pa = *(const bf16x8*)&pS[wave * 384 + c15 * 24 + (quad & 1) * 8];
                vb = *(const bf16x8*)&vtS[(h * 16 + c15) * 24 + (quad & 1) * 8];
            }
            f32x4 xs = {0.f, 0.f, 0.f, 0.f};
            xs = MFMA(pa, vb, xs);
            #pragma unroll
            for (int r = 0; r < 4; ++r) {
                const int tok = quad * 4 + r;
                float val = xs[r] + greg[r] * vblk;
                mhiS[p][tok * 136 + h * 16 + c15] = f2bf_rn(val);
            }
        }

        // ---- stage next block's x into xS[p^1] (safe: dbuf) ----
        if (more) {
            int row = tid >> 5, c4 = tid & 31;
            int off = row * 128 + (((c4 >> 1) ^ (row & 7)) << 3) + ((c4 & 1) << 2);
            us4 hi;
            hi[0] = f2bf_rn(xv_n.x); hi[1] = f2bf_rn(xv_n.y);
            hi[2] = f2bf_rn(xv_n.z); hi[3] = f2bf_rn(xv_n.w);
            *(us4*)&xS[p ^ 1][off] = hi;
        }
        mvH = mv_n;
        evH = ev_n;

        __syncthreads();   // THE barrier: mhiS[p], ewS[p^1], logitS[p^1], xS[p^1]

        // ---- output projection (resident Wt; overlaps next iter's front half) ----
        {
            bf16x8 mh[4];
            #pragma unroll
            for (int kk = 0; kk < 4; ++kk)
                mh[kk] = *(const bf16x8*)&mhiS[p][c15 * 136 + kk * 32 + quad * 8];
            f32x4 acc = {0.f, 0.f, 0.f, 0.f};
            #pragma unroll
            for (int kk = 0; kk < 4; ++kk) acc = MFMA(mh[kk], Wt[kk], acc);
            float* op = out + (size_t)bid * 2048;
            #pragma unroll
            for (int r = 0; r < 4; ++r)
                op[(quad * 4 + r) * 128 + wave * 16 + c15] = acc[r] + bpv;
        }
    }
}

extern "C" void kernel_launch(void* const* d_in, const int* in_sizes, int n_in,
                              void* d_out, int out_size, void* d_ws, size_t ws_size,
                              hipStream_t stream) {
    const float* x     = (const float*)d_in[0];
    const int*   amask = (const int*)  d_in[1];
    const float* edge  = (const float*)d_in[2];
    const float* Wqkv  = (const float*)d_in[3];
    const float* bqkv  = (const float*)d_in[4];
    const float* Wproj = (const float*)d_in[5];
    const float* bproj = (const float*)d_in[6];
    const float* eg_w1 = (const float*)d_in[7];
    const float* eg_b1 = (const float*)d_in[8];
    const float* eg_w2 = (const float*)d_in[9];
    const float* eg_b2 = (const float*)d_in[10];
    const float* Wbr   = (const float*)d_in[11];
    const float* bbr   = (const float*)d_in[12];
    float* outp = (float*)d_out;

    unsigned short* Wbig = (unsigned short*)d_ws;                      // 400*128 bf16
    unsigned short* Wp   = (unsigned short*)((char*)d_ws + 400 * 128 * 2);

    hipLaunchKernelGGL(prep_kernel, dim3(264), dim3(256), 0, stream,
                       Wqkv, Wbr, Wproj, Wbig, Wp);
    hipLaunchKernelGGL(leaf_main, dim3(8192 / NITER), dim3(512), 0, stream,
                       x, amask, edge, Wbig, Wp, bqkv, bproj,
                       eg_w1, eg_b1, eg_w2, eg_b2, bbr, outp);
}

// Round 14
// 122.545 us; speedup vs baseline: 1.7001x; 1.0605x over previous
//
#include <hip/hip_runtime.h>
#include <hip/hip_bf16.h>
#include <math.h>

// B=4, NB=2048 -> 8192 leaf blocks of L=16 tokens x C=128; H=8 heads x D=16.
// 512 threads (8 waves), NITER=4 blocks/WG, 2 barriers/iter.
// Key trick: q,k computed via SWAPPED-operand MFMA (W as A, x as B) so their
// D-layout equals the 16x16x16 QK^T fragment layout in-register; scores' D-layout
// equals PV's A-fragment layout; v's natural D-layout equals PV's B-fragment.
// => q/k/v/P never touch LDS. MLP weights staged in LDS once. Max-free softmax.
typedef __attribute__((ext_vector_type(8))) short bf16x8;
typedef __attribute__((ext_vector_type(4))) short bf16x4;
typedef __attribute__((ext_vector_type(4))) float f32x4;
typedef __attribute__((ext_vector_type(4))) unsigned short us4;

#define NITER 4

static __device__ __forceinline__ unsigned short f2bf_rn(float f) {
    union { __hip_bfloat16 h; unsigned short u; } cv;
    cv.h = __float2bfloat16(f);
    return cv.u;
}
static __device__ __forceinline__ float bf2f(unsigned short u) {
    union { unsigned int i; float f; } cv;
    cv.i = ((unsigned int)u) << 16;
    return cv.f;
}
static __device__ __forceinline__ f32x4 MFMA(bf16x8 a, bf16x8 b, f32x4 c) {
    return __builtin_amdgcn_mfma_f32_16x16x32_bf16(a, b, c, 0, 0, 0);
}
static __device__ __forceinline__ f32x4 MFMA16(bf16x4 a, bf16x4 b, f32x4 c) {
#if __has_builtin(__builtin_amdgcn_mfma_f32_16x16x16bf16_1k)
    return __builtin_amdgcn_mfma_f32_16x16x16bf16_1k(a, b, c, 0, 0, 0);
#elif __has_builtin(__builtin_amdgcn_mfma_f32_16x16x16_bf16)
    return __builtin_amdgcn_mfma_f32_16x16x16_bf16(a, b, c, 0, 0, 0);
#else
    f32x4 d;
    asm("v_mfma_f32_16x16x16_bf16 %0, %1, %2, %3"
        : "=v"(d) : "v"(a), "v"(b), "v"(c));
    return d;
#endif
}
static __device__ __forceinline__ float sigmoid_fast(float t) {
    return __builtin_amdgcn_rcpf(1.f + __expf(-t));
}

// ---- prep: Wbig = bf16([Wqkv(384); Wbr(8); zeros(8)]) [400][128]; Wp = bf16(Wproj)
__global__ __launch_bounds__(256) void prep_kernel(
    const float* __restrict__ Wqkv, const float* __restrict__ Wbr,
    const float* __restrict__ Wproj,
    unsigned short* __restrict__ Wbig, unsigned short* __restrict__ Wp)
{
    int i = blockIdx.x * 256 + threadIdx.x;
    if (i < 400 * 128) {
        int n = i >> 7, k = i & 127;
        float v = (n < 384) ? Wqkv[i] : (n < 392 ? Wbr[(n - 384) * 128 + k] : 0.f);
        Wbig[i] = f2bf_rn(v);
    } else {
        int j = i - 400 * 128;
        if (j < 128 * 128) Wp[j] = f2bf_rn(Wproj[j]);
    }
}

__global__ __launch_bounds__(512) void leaf_main(
    const float* __restrict__ x, const int* __restrict__ mask,
    const float* __restrict__ edge,
    const unsigned short* __restrict__ Wbig, const unsigned short* __restrict__ Wp,
    const float* __restrict__ bqkv, const float* __restrict__ bproj,
    const float* __restrict__ eg_w1, const float* __restrict__ eg_b1,
    const float* __restrict__ eg_w2, const float* __restrict__ eg_b2,
    const float* __restrict__ bbr, float* __restrict__ out)
{
    __shared__ unsigned short xS[16 * 128];      // x stage (bf16, swizzled)
    __shared__ unsigned short mhiS[16 * 136];    // x_mid rounded bf16
    __shared__ unsigned short ewS[8 * 256];      // [h][q*16+k]
    __shared__ float logitS[256];                // [q*16+k]
    __shared__ float mlpW1[16 * 4];              // staged MLP weights
    __shared__ float mlpB1[16];
    __shared__ float mlpW2T[16 * 8];             // eg_w2 transposed [j][h]
    // total ~15.5 KB

    const int tid  = threadIdx.x;
    const int lane = tid & 63;
    const int wave = tid >> 6;
    const int c15  = lane & 15;
    const int quad = lane >> 4;
    const int bid0 = blockIdx.x * NITER;

    // iteration-invariant scalars (note: q/k biases are per-d = quad*4+r based)
    const f32x4 bqv = *(const f32x4*)&bqkv[wave * 16 + quad * 4];
    const f32x4 bkv = *(const f32x4*)&bqkv[128 + wave * 16 + quad * 4];
    const float bq2 = bqkv[256 + wave * 16 + c15];
    const float bgate = bbr[c15 & 7];
    const float bpv = bproj[wave * 16 + c15];

    // stage MLP weights into LDS (once per WG)
    if (tid < 16) {
        const int j = tid;
        #pragma unroll
        for (int i = 0; i < 4; ++i) mlpW1[j * 4 + i] = eg_w1[j * 4 + i];
        mlpB1[j] = eg_b1[j];
        #pragma unroll
        for (int h = 0; h < 8; ++h) mlpW2T[j * 8 + h] = eg_w2[h * 16 + j];
    }

    // rolling weight slots: entry invariant {slot0=q-tile, slot1=k-tile}
    bf16x8 Bt[2][4];
    const unsigned short* wbase = Wbig + c15 * 128 + quad * 8;
    {
        const unsigned short* w0 = wbase + (wave * 16) * 128;
        #pragma unroll
        for (int kk = 0; kk < 4; ++kk) Bt[0][kk] = *(const bf16x8*)(w0 + kk * 32);
        const unsigned short* w1 = wbase + ((8 + wave) * 16) * 128;
        #pragma unroll
        for (int kk = 0; kk < 4; ++kk) Bt[1][kk] = *(const bf16x8*)(w1 + kk * 32);
    }

    // prologue: block 0 inputs
    int mv = 0;
    float4 evv = make_float4(0.f, 0.f, 0.f, 0.f);
    if (tid < 256) {
        mv  = mask[(size_t)bid0 * 256 + tid];
        evv = *(const float4*)&edge[((size_t)bid0 * 256 + tid) * 4];
    }
    float4 xv = ((const float4*)(x + (size_t)bid0 * 2048))[tid];
    {
        int row = tid >> 5, c4 = tid & 31;
        int off = row * 128 + (((c4 >> 1) ^ (row & 7)) << 3) + ((c4 & 1) << 2);
        us4 hi;
        hi[0] = f2bf_rn(xv.x); hi[1] = f2bf_rn(xv.y);
        hi[2] = f2bf_rn(xv.z); hi[3] = f2bf_rn(xv.w);
        *(us4*)&xS[off] = hi;
    }
    __syncthreads();   // prologue barrier: x0 + MLP tables staged

    #pragma unroll 1
    for (int it = 0; it < NITER; ++it) {
        const int bid = bid0 + it;
        const bool more = (it + 1 < NITER);

        // next-block loads (retire under this iteration's compute)
        float4 xv_n = make_float4(0.f, 0.f, 0.f, 0.f);
        int mv_n = 0;
        float4 ev_n = make_float4(0.f, 0.f, 0.f, 0.f);
        if (more) {
            xv_n = ((const float4*)(x + (size_t)(bid + 1) * 2048))[tid];
            if (tid < 256) {
                mv_n = mask[(size_t)(bid + 1) * 256 + tid];
                ev_n = *(const float4*)&edge[((size_t)(bid + 1) * 256 + tid) * 4];
            }
        }

        // ---- edge-gate MLP (poly gelu, LDS-staged weights) + mask/logits ----
        if (tid < 256) {
            const int q = tid >> 4, k = tid & 15;
            int s = mv;
            s += __shfl_xor(s, 1); s += __shfl_xor(s, 2);
            s += __shfl_xor(s, 4); s += __shfl_xor(s, 8);
            float m = (float)mv;
            if (q == k && s < 1) m = 1.f;
            float bp0, bp1, bp2, bp3;
            if (q == k) { bp0 = bp1 = bp2 = 0.f; bp3 = 1.f; }
            else        { bp0 = evv.x; bp1 = evv.y; bp2 = evv.z; bp3 = evv.w; }
            logitS[tid] = (m == 0.f) ? -INFINITY : bp3;
            float ew[8];
            #pragma unroll
            for (int h = 0; h < 8; ++h) ew[h] = eg_b2[h];
            #pragma unroll
            for (int j = 0; j < 16; ++j) {
                const f32x4 w1j = *(const f32x4*)&mlpW1[j * 4];
                float z = __builtin_fmaf(w1j[0], bp0,
                          __builtin_fmaf(w1j[1], bp1,
                          __builtin_fmaf(w1j[2], bp2,
                          __builtin_fmaf(w1j[3], bp3, mlpB1[j]))));
                float u = z * z;
                float w = __builtin_fmaf(-0.0664904f, u, 0.3989423f);
                float g = z * __builtin_fmaf(z, w, 0.5f);
                const f32x4 wa = *(const f32x4*)&mlpW2T[j * 8];
                const f32x4 wb = *(const f32x4*)&mlpW2T[j * 8 + 4];
                ew[0] = __builtin_fmaf(wa[0], g, ew[0]);
                ew[1] = __builtin_fmaf(wa[1], g, ew[1]);
                ew[2] = __builtin_fmaf(wa[2], g, ew[2]);
                ew[3] = __builtin_fmaf(wa[3], g, ew[3]);
                ew[4] = __builtin_fmaf(wb[0], g, ew[4]);
                ew[5] = __builtin_fmaf(wb[1], g, ew[5]);
                ew[6] = __builtin_fmaf(wb[2], g, ew[6]);
                ew[7] = __builtin_fmaf(wb[3], g, ew[7]);
            }
            #pragma unroll
            for (int h = 0; h < 8; ++h)
                ewS[h * 256 + tid] = (m == 0.f) ? (unsigned short)0
                                   : (unsigned short)(__float_as_uint(ew[h]) >> 16);
        }

        // ---- x B-fragments from xS (same regs serve as A or B operand) ----
        bf16x8 ah[4];
        #pragma unroll
        for (int kk = 0; kk < 4; ++kk) {
            int off = c15 * 128 + (((kk * 4 + quad) ^ (c15 & 7)) << 3);
            ah[kk] = *(const bf16x8*)&xS[off];
        }

        bf16x4 qa, ka, va;
        float vblk;
        float greg[4];

        // ---- tile q: SWAPPED (W as A, x as B) -> Q[tok=c15][d=quad*4+r] ----
        {
            f32x4 acc = {0.f, 0.f, 0.f, 0.f};
            #pragma unroll
            for (int kk = 0; kk < 4; ++kk) acc = MFMA(Bt[0][kk], ah[kk], acc);
            const unsigned short* w2 = wbase + ((16 + wave) * 16) * 128;  // v-tile
            #pragma unroll
            for (int kk = 0; kk < 4; ++kk) Bt[0][kk] = *(const bf16x8*)(w2 + kk * 32);
            #pragma unroll
            for (int r = 0; r < 4; ++r) qa[r] = (short)f2bf_rn(acc[r] + bqv[r]);
        }

        // ---- tile k: SWAPPED -> K[tok=c15][d=quad*4+r] ----
        {
            f32x4 acc = {0.f, 0.f, 0.f, 0.f};
            #pragma unroll
            for (int kk = 0; kk < 4; ++kk) acc = MFMA(Bt[1][kk], ah[kk], acc);
            const unsigned short* w3 = wbase + 384 * 128;                 // gate tile
            #pragma unroll
            for (int kk = 0; kk < 4; ++kk) Bt[1][kk] = *(const bf16x8*)(w3 + kk * 32);
            #pragma unroll
            for (int r = 0; r < 4; ++r) ka[r] = (short)f2bf_rn(acc[r] + bkv[r]);
        }

        // ---- tile v: normal -> V[tok=quad*4+r][d=c15]; v_blk in-register ----
        {
            f32x4 acc = {0.f, 0.f, 0.f, 0.f};
            #pragma unroll
            for (int kk = 0; kk < 4; ++kk) acc = MFMA(ah[kk], Bt[0][kk], acc);
            const unsigned short* w0 = wbase + (wave * 16) * 128;         // next q
            #pragma unroll
            for (int kk = 0; kk < 4; ++kk) Bt[0][kk] = *(const bf16x8*)(w0 + kk * 32);
            #pragma unroll
            for (int r = 0; r < 4; ++r) va[r] = (short)f2bf_rn(acc[r] + bq2);
            float s = acc[0] + acc[1] + acc[2] + acc[3];
            s += __shfl_xor(s, 16);
            s += __shfl_xor(s, 32);
            vblk = s * 0.0625f + bq2;     // v_blk[d=c15] of head `wave`
        }

        // ---- tile gate: normal; keep own column via shuffle ----
        {
            f32x4 acc = {0.f, 0.f, 0.f, 0.f};
            #pragma unroll
            for (int kk = 0; kk < 4; ++kk) acc = MFMA(ah[kk], Bt[1][kk], acc);
            const unsigned short* w1 = wbase + ((8 + wave) * 16) * 128;   // next k
            #pragma unroll
            for (int kk = 0; kk < 4; ++kk) Bt[1][kk] = *(const bf16x8*)(w1 + kk * 32);
            const int src = (lane & 48) | wave;
            #pragma unroll
            for (int r = 0; r < 4; ++r) {
                float sg = sigmoid_fast(acc[r] + bgate);
                greg[r] = __shfl(sg, src);        // g[tok=quad*4+r][h=wave]
            }
        }
        __syncthreads();   // barrier B: ewS/logitS visible; xS reads done

        // stage NEXT block's x (overlaps attention; visibility via barrier C)
        if (more) {
            int row = tid >> 5, c4 = tid & 31;
            int off = row * 128 + (((c4 >> 1) ^ (row & 7)) << 3) + ((c4 & 1) << 2);
            us4 hi;
            hi[0] = f2bf_rn(xv_n.x); hi[1] = f2bf_rn(xv_n.y);
            hi[2] = f2bf_rn(xv_n.z); hi[3] = f2bf_rn(xv_n.w);
            *(us4*)&xS[off] = hi;
        }

        // proj weights prefetch (retire under attention)
        bf16x8 Wt[4];
        {
            const unsigned short* wp = Wp + (wave * 16 + c15) * 128 + quad * 8;
            #pragma unroll
            for (int kk = 0; kk < 4; ++kk) Wt[kk] = *(const bf16x8*)(wp + kk * 32);
        }

        // ---- attention (head h = wave), fully in-register ----
        {
            f32x4 sc = {0.f, 0.f, 0.f, 0.f};
            sc = MFMA16(ka, qa, sc);          // D[k=quad*4+r][q=c15]
            const f32x4 lg = *(const f32x4*)&logitS[c15 * 16 + quad * 4];
            const us4 ew4 = *(const us4*)&ewS[wave * 256 + c15 * 16 + quad * 4];
            // max-free softmax (|s| <~ 15, f32 exp safe; -inf -> 0)
            float e0 = __expf(__builtin_fmaf(sc[0], 0.25f, lg[0]));
            float e1 = __expf(__builtin_fmaf(sc[1], 0.25f, lg[1]));
            float e2 = __expf(__builtin_fmaf(sc[2], 0.25f, lg[2]));
            float e3 = __expf(__builtin_fmaf(sc[3], 0.25f, lg[3]));
            float sm = (e0 + e1) + (e2 + e3);
            sm += __shfl_xor(sm, 16);
            sm += __shfl_xor(sm, 32);
            const float inv = __builtin_amdgcn_rcpf(sm);
            bf16x4 pa;   // P^T fragment == scores D layout: same lane, same elems
            pa[0] = (short)f2bf_rn(__builtin_fmaf(e0, inv, bf2f(ew4[0])));
            pa[1] = (short)f2bf_rn(__builtin_fmaf(e1, inv, bf2f(ew4[1])));
            pa[2] = (short)f2bf_rn(__builtin_fmaf(e2, inv, bf2f(ew4[2])));
            pa[3] = (short)f2bf_rn(__builtin_fmaf(e3, inv, bf2f(ew4[3])));
            f32x4 xs = {0.f, 0.f, 0.f, 0.f};
            xs = MFMA16(pa, va, xs);          // D[q=quad*4+r][d=c15]
            #pragma unroll
            for (int r = 0; r < 4; ++r) {
                const int tok = quad * 4 + r;
                float val = xs[r] + greg[r] * vblk;
                mhiS[tok * 136 + wave * 16 + c15] = f2bf_rn(val);
            }
        }
        __syncthreads();   // barrier C: x_mid + next-x staged visible

        // ---- output projection ----
        {
            bf16x8 mh[4];
            #pragma unroll
            for (int kk = 0; kk < 4; ++kk)
                mh[kk] = *(const bf16x8*)&mhiS[c15 * 136 + kk * 32 + quad * 8];
            f32x4 acc = {0.f, 0.f, 0.f, 0.f};
            #pragma unroll
            for (int kk = 0; kk < 4; ++kk) acc = MFMA(mh[kk], Wt[kk], acc);
            float* op = out + (size_t)bid * 2048;
            #pragma unroll
            for (int r = 0; r < 4; ++r)
                op[(quad * 4 + r) * 128 + wave * 16 + c15] = acc[r] + bpv;
        }

        mv = mv_n;
        evv = ev_n;
    }
}

extern "C" void kernel_launch(void* const* d_in, const int* in_sizes, int n_in,
                              void* d_out, int out_size, void* d_ws, size_t ws_size,
                              hipStream_t stream) {
    const float* x     = (const float*)d_in[0];
    const int*   amask = (const int*)  d_in[1];
    const float* edge  = (const float*)d_in[2];
    const float* Wqkv  = (const float*)d_in[3];
    const float* bqkv  = (const float*)d_in[4];
    const float* Wproj = (const float*)d_in[5];
    const float* bproj = (const float*)d_in[6];
    const float* eg_w1 = (const float*)d_in[7];
    const float* eg_b1 = (const float*)d_in[8];
    const float* eg_w2 = (const float*)d_in[9];
    const float* eg_b2 = (const float*)d_in[10];
    const float* Wbr   = (const float*)d_in[11];
    const float* bbr   = (const float*)d_in[12];
    float* outp = (float*)d_out;

    unsigned short* Wbig = (unsigned short*)d_ws;                      // 400*128 bf16
    unsigned short* Wp   = (unsigned short*)((char*)d_ws + 400 * 128 * 2);

    hipLaunchKernelGGL(prep_kernel, dim3(264), dim3(256), 0, stream,
                       Wqkv, Wbr, Wproj, Wbig, Wp);
    hipLaunchKernelGGL(leaf_main, dim3(8192 / NITER), dim3(512), 0, stream,
                       x, amask, edge, Wbig, Wp, bqkv, bproj,
                       eg_w1, eg_b1, eg_w2, eg_b2, bbr, outp);
}

// Round 15
// 96.111 us; speedup vs baseline: 2.1676x; 1.2750x over previous
//
#include <hip/hip_runtime.h>
#include <hip/hip_bf16.h>
#include <math.h>

// B=4, NB=2048 -> 8192 leaf blocks of L=16 tokens x C=128; H=8 heads x D=16.
// 512 threads (8 waves), NITER=8 blocks/WG (grid 1024), 2 barriers/iter.
// q/k computed with SWAPPED-operand MFMA so q/k/v/P stay in registers (r14).
// NEW: Bq/Bk/Bv/Wt register-resident for the WG lifetime (loaded once, natural
// VGPR allocation, no bounds hint); gate tile re-loaded at iteration top.
// Mask row-sum via __ballot+popcount (kills the 4-deep shfl chain).
typedef __attribute__((ext_vector_type(8))) short bf16x8;
typedef __attribute__((ext_vector_type(4))) short bf16x4;
typedef __attribute__((ext_vector_type(4))) float f32x4;
typedef __attribute__((ext_vector_type(4))) unsigned short us4;

#define NITER 8

static __device__ __forceinline__ unsigned short f2bf_rn(float f) {
    union { __hip_bfloat16 h; unsigned short u; } cv;
    cv.h = __float2bfloat16(f);
    return cv.u;
}
static __device__ __forceinline__ float bf2f(unsigned short u) {
    union { unsigned int i; float f; } cv;
    cv.i = ((unsigned int)u) << 16;
    return cv.f;
}
static __device__ __forceinline__ f32x4 MFMA(bf16x8 a, bf16x8 b, f32x4 c) {
    return __builtin_amdgcn_mfma_f32_16x16x32_bf16(a, b, c, 0, 0, 0);
}
static __device__ __forceinline__ f32x4 MFMA16(bf16x4 a, bf16x4 b, f32x4 c) {
#if __has_builtin(__builtin_amdgcn_mfma_f32_16x16x16bf16_1k)
    return __builtin_amdgcn_mfma_f32_16x16x16bf16_1k(a, b, c, 0, 0, 0);
#elif __has_builtin(__builtin_amdgcn_mfma_f32_16x16x16_bf16)
    return __builtin_amdgcn_mfma_f32_16x16x16_bf16(a, b, c, 0, 0, 0);
#else
    f32x4 d;
    asm("v_mfma_f32_16x16x16_bf16 %0, %1, %2, %3"
        : "=v"(d) : "v"(a), "v"(b), "v"(c));
    return d;
#endif
}
static __device__ __forceinline__ float sigmoid_fast(float t) {
    return __builtin_amdgcn_rcpf(1.f + __expf(-t));
}

// ---- prep: Wbig = bf16([Wqkv(384); Wbr(8); zeros(8)]) [400][128]; Wp = bf16(Wproj)
__global__ __launch_bounds__(256) void prep_kernel(
    const float* __restrict__ Wqkv, const float* __restrict__ Wbr,
    const float* __restrict__ Wproj,
    unsigned short* __restrict__ Wbig, unsigned short* __restrict__ Wp)
{
    int i = blockIdx.x * 256 + threadIdx.x;
    if (i < 400 * 128) {
        int n = i >> 7, k = i & 127;
        float v = (n < 384) ? Wqkv[i] : (n < 392 ? Wbr[(n - 384) * 128 + k] : 0.f);
        Wbig[i] = f2bf_rn(v);
    } else {
        int j = i - 400 * 128;
        if (j < 128 * 128) Wp[j] = f2bf_rn(Wproj[j]);
    }
}

__global__ __launch_bounds__(512) void leaf_main(
    const float* __restrict__ x, const int* __restrict__ mask,
    const float* __restrict__ edge,
    const unsigned short* __restrict__ Wbig, const unsigned short* __restrict__ Wp,
    const float* __restrict__ bqkv, const float* __restrict__ bproj,
    const float* __restrict__ eg_w1, const float* __restrict__ eg_b1,
    const float* __restrict__ eg_w2, const float* __restrict__ eg_b2,
    const float* __restrict__ bbr, float* __restrict__ out)
{
    __shared__ unsigned short xS[16 * 128];      // x stage (bf16, swizzled)
    __shared__ unsigned short mhiS[16 * 136];    // x_mid rounded bf16
    __shared__ unsigned short ewS[8 * 256];      // [h][q*16+k]
    __shared__ float logitS[256];                // [q*16+k]
    __shared__ float mlpW1[16 * 4];              // staged MLP weights
    __shared__ float mlpB1[16];
    __shared__ float mlpW2T[16 * 8];             // eg_w2 transposed [j][h]
    // total ~15.5 KB

    const int tid  = threadIdx.x;
    const int lane = tid & 63;
    const int wave = tid >> 6;
    const int c15  = lane & 15;
    const int quad = lane >> 4;
    const int bid0 = blockIdx.x * NITER;

    // iteration-invariant scalars (q/k biases are per-d = quad*4+r based)
    const f32x4 bqv = *(const f32x4*)&bqkv[wave * 16 + quad * 4];
    const f32x4 bkv = *(const f32x4*)&bqkv[128 + wave * 16 + quad * 4];
    const float bq2 = bqkv[256 + wave * 16 + c15];
    const float bgate = bbr[c15 & 7];
    const float bpv = bproj[wave * 16 + c15];

    // stage MLP weights into LDS (once per WG)
    if (tid < 16) {
        const int j = tid;
        #pragma unroll
        for (int i = 0; i < 4; ++i) mlpW1[j * 4 + i] = eg_w1[j * 4 + i];
        mlpB1[j] = eg_b1[j];
        #pragma unroll
        for (int h = 0; h < 8; ++h) mlpW2T[j * 8 + h] = eg_w2[h * 16 + j];
    }

    // ---- REGISTER-RESIDENT weight tiles (once per WG; natural allocation) ----
    const unsigned short* wbase = Wbig + c15 * 128 + quad * 8;
    bf16x8 Bq[4], Bk[4], Bv[4], Wt[4];
    {
        const unsigned short* wq = wbase + (wave * 16) * 128;
        const unsigned short* wk = wbase + ((8 + wave) * 16) * 128;
        const unsigned short* wv = wbase + ((16 + wave) * 16) * 128;
        const unsigned short* wp = Wp + (wave * 16 + c15) * 128 + quad * 8;
        #pragma unroll
        for (int kk = 0; kk < 4; ++kk) {
            Bq[kk] = *(const bf16x8*)(wq + kk * 32);
            Bk[kk] = *(const bf16x8*)(wk + kk * 32);
            Bv[kk] = *(const bf16x8*)(wv + kk * 32);
            Wt[kk] = *(const bf16x8*)(wp + kk * 32);
        }
    }
    const unsigned short* wg = wbase + 384 * 128;   // gate tile (per-iter load)

    // prologue: block 0 inputs
    int mv = 0;
    float4 evv = make_float4(0.f, 0.f, 0.f, 0.f);
    if (tid < 256) {
        mv  = mask[(size_t)bid0 * 256 + tid];
        evv = *(const float4*)&edge[((size_t)bid0 * 256 + tid) * 4];
    }
    float4 xv = ((const float4*)(x + (size_t)bid0 * 2048))[tid];
    {
        int row = tid >> 5, c4 = tid & 31;
        int off = row * 128 + (((c4 >> 1) ^ (row & 7)) << 3) + ((c4 & 1) << 2);
        us4 hi;
        hi[0] = f2bf_rn(xv.x); hi[1] = f2bf_rn(xv.y);
        hi[2] = f2bf_rn(xv.z); hi[3] = f2bf_rn(xv.w);
        *(us4*)&xS[off] = hi;
    }
    __syncthreads();   // prologue barrier: x0 + MLP tables staged

    #pragma unroll 1
    for (int it = 0; it < NITER; ++it) {
        const int bid = bid0 + it;
        const bool more = (it + 1 < NITER);

        // gate tile load (issued at top; consumed ~1.5k cycles later)
        bf16x8 Bg[4];
        #pragma unroll
        for (int kk = 0; kk < 4; ++kk) Bg[kk] = *(const bf16x8*)(wg + kk * 32);

        // next-block loads (retire under this iteration's compute)
        float4 xv_n = make_float4(0.f, 0.f, 0.f, 0.f);
        int mv_n = 0;
        float4 ev_n = make_float4(0.f, 0.f, 0.f, 0.f);
        if (more) {
            xv_n = ((const float4*)(x + (size_t)(bid + 1) * 2048))[tid];
            if (tid < 256) {
                mv_n = mask[(size_t)(bid + 1) * 256 + tid];
                ev_n = *(const float4*)&edge[((size_t)(bid + 1) * 256 + tid) * 4];
            }
        }

        // ---- edge-gate MLP (poly gelu, LDS weights, ballot row-sum) ----
        if (tid < 256) {
            const int q = tid >> 4, k = tid & 15;
            unsigned long long b = __ballot(mv != 0);
            int rs = __popcll((b >> (lane & 48)) & 0xFFFFull);
            float m = (float)mv;
            if (q == k && rs < 1) m = 1.f;
            float bp0, bp1, bp2, bp3;
            if (q == k) { bp0 = bp1 = bp2 = 0.f; bp3 = 1.f; }
            else        { bp0 = evv.x; bp1 = evv.y; bp2 = evv.z; bp3 = evv.w; }
            logitS[tid] = (m == 0.f) ? -INFINITY : bp3;
            float ew[8];
            #pragma unroll
            for (int h = 0; h < 8; ++h) ew[h] = eg_b2[h];
            #pragma unroll
            for (int j = 0; j < 16; ++j) {
                const f32x4 w1j = *(const f32x4*)&mlpW1[j * 4];
                float z = __builtin_fmaf(w1j[0], bp0,
                          __builtin_fmaf(w1j[1], bp1,
                          __builtin_fmaf(w1j[2], bp2,
                          __builtin_fmaf(w1j[3], bp3, mlpB1[j]))));
                float u = z * z;
                float w = __builtin_fmaf(-0.0664904f, u, 0.3989423f);
                float g = z * __builtin_fmaf(z, w, 0.5f);
                const f32x4 wa = *(const f32x4*)&mlpW2T[j * 8];
                const f32x4 wb = *(const f32x4*)&mlpW2T[j * 8 + 4];
                ew[0] = __builtin_fmaf(wa[0], g, ew[0]);
                ew[1] = __builtin_fmaf(wa[1], g, ew[1]);
                ew[2] = __builtin_fmaf(wa[2], g, ew[2]);
                ew[3] = __builtin_fmaf(wa[3], g, ew[3]);
                ew[4] = __builtin_fmaf(wb[0], g, ew[4]);
                ew[5] = __builtin_fmaf(wb[1], g, ew[5]);
                ew[6] = __builtin_fmaf(wb[2], g, ew[6]);
                ew[7] = __builtin_fmaf(wb[3], g, ew[7]);
            }
            #pragma unroll
            for (int h = 0; h < 8; ++h)
                ewS[h * 256 + tid] = (m == 0.f) ? (unsigned short)0
                                   : (unsigned short)(__float_as_uint(ew[h]) >> 16);
        }

        // ---- x fragments from xS (serve as A or B operand) ----
        bf16x8 ah[4];
        #pragma unroll
        for (int kk = 0; kk < 4; ++kk) {
            int off = c15 * 128 + (((kk * 4 + quad) ^ (c15 & 7)) << 3);
            ah[kk] = *(const bf16x8*)&xS[off];
        }

        bf16x4 qa, ka, va;
        float vblk;
        float greg[4];

        // ---- tile q: SWAPPED (W as A, x as B) -> Q[tok=c15][d=quad*4+r] ----
        {
            f32x4 acc = {0.f, 0.f, 0.f, 0.f};
            #pragma unroll
            for (int kk = 0; kk < 4; ++kk) acc = MFMA(Bq[kk], ah[kk], acc);
            #pragma unroll
            for (int r = 0; r < 4; ++r) qa[r] = (short)f2bf_rn(acc[r] + bqv[r]);
        }

        // ---- tile k: SWAPPED -> K[tok=c15][d=quad*4+r] ----
        {
            f32x4 acc = {0.f, 0.f, 0.f, 0.f};
            #pragma unroll
            for (int kk = 0; kk < 4; ++kk) acc = MFMA(Bk[kk], ah[kk], acc);
            #pragma unroll
            for (int r = 0; r < 4; ++r) ka[r] = (short)f2bf_rn(acc[r] + bkv[r]);
        }

        // ---- tile v: normal -> V[tok=quad*4+r][d=c15]; v_blk in-register ----
        {
            f32x4 acc = {0.f, 0.f, 0.f, 0.f};
            #pragma unroll
            for (int kk = 0; kk < 4; ++kk) acc = MFMA(ah[kk], Bv[kk], acc);
            #pragma unroll
            for (int r = 0; r < 4; ++r) va[r] = (short)f2bf_rn(acc[r] + bq2);
            float s = acc[0] + acc[1] + acc[2] + acc[3];
            s += __shfl_xor(s, 16);
            s += __shfl_xor(s, 32);
            vblk = s * 0.0625f + bq2;     // v_blk[d=c15] of head `wave`
        }

        // ---- tile gate: normal; keep own column via shuffle ----
        {
            f32x4 acc = {0.f, 0.f, 0.f, 0.f};
            #pragma unroll
            for (int kk = 0; kk < 4; ++kk) acc = MFMA(ah[kk], Bg[kk], acc);
            const int src = (lane & 48) | wave;
            #pragma unroll
            for (int r = 0; r < 4; ++r) {
                float sg = sigmoid_fast(acc[r] + bgate);
                greg[r] = __shfl(sg, src);        // g[tok=quad*4+r][h=wave]
            }
        }
        __syncthreads();   // barrier B: ewS/logitS visible; xS reads done

        // stage NEXT block's x (overlaps attention; visibility via barrier C)
        if (more) {
            int row = tid >> 5, c4 = tid & 31;
            int off = row * 128 + (((c4 >> 1) ^ (row & 7)) << 3) + ((c4 & 1) << 2);
            us4 hi;
            hi[0] = f2bf_rn(xv_n.x); hi[1] = f2bf_rn(xv_n.y);
            hi[2] = f2bf_rn(xv_n.z); hi[3] = f2bf_rn(xv_n.w);
            *(us4*)&xS[off] = hi;
        }

        // ---- attention (head h = wave), fully in-register ----
        {
            f32x4 sc = {0.f, 0.f, 0.f, 0.f};
            sc = MFMA16(ka, qa, sc);          // D[k=quad*4+r][q=c15]
            const f32x4 lg = *(const f32x4*)&logitS[c15 * 16 + quad * 4];
            const us4 ew4 = *(const us4*)&ewS[wave * 256 + c15 * 16 + quad * 4];
            // max-free softmax (|s| <~ 15, f32 exp safe; -inf -> 0)
            float e0 = __expf(__builtin_fmaf(sc[0], 0.25f, lg[0]));
            float e1 = __expf(__builtin_fmaf(sc[1], 0.25f, lg[1]));
            float e2 = __expf(__builtin_fmaf(sc[2], 0.25f, lg[2]));
            float e3 = __expf(__builtin_fmaf(sc[3], 0.25f, lg[3]));
            float sm = (e0 + e1) + (e2 + e3);
            sm += __shfl_xor(sm, 16);
            sm += __shfl_xor(sm, 32);
            const float inv = __builtin_amdgcn_rcpf(sm);
            bf16x4 pa;   // P fragment == scores D layout (same lane, same elems)
            pa[0] = (short)f2bf_rn(__builtin_fmaf(e0, inv, bf2f(ew4[0])));
            pa[1] = (short)f2bf_rn(__builtin_fmaf(e1, inv, bf2f(ew4[1])));
            pa[2] = (short)f2bf_rn(__builtin_fmaf(e2, inv, bf2f(ew4[2])));
            pa[3] = (short)f2bf_rn(__builtin_fmaf(e3, inv, bf2f(ew4[3])));
            f32x4 xs = {0.f, 0.f, 0.f, 0.f};
            xs = MFMA16(pa, va, xs);          // D[q=quad*4+r][d=c15]
            #pragma unroll
            for (int r = 0; r < 4; ++r) {
                const int tok = quad * 4 + r;
                float val = xs[r] + greg[r] * vblk;
                mhiS[tok * 136 + wave * 16 + c15] = f2bf_rn(val);
            }
        }
        __syncthreads();   // barrier C: x_mid + next-x staged visible

        // ---- output projection (resident Wt) ----
        {
            bf16x8 mh[4];
            #pragma unroll
            for (int kk = 0; kk < 4; ++kk)
                mh[kk] = *(const bf16x8*)&mhiS[c15 * 136 + kk * 32 + quad * 8];
            f32x4 acc = {0.f, 0.f, 0.f, 0.f};
            #pragma unroll
            for (int kk = 0; kk < 4; ++kk) acc = MFMA(mh[kk], Wt[kk], acc);
            float* op = out + (size_t)bid * 2048;
            #pragma unroll
            for (int r = 0; r < 4; ++r)
                op[(quad * 4 + r) * 128 + wave * 16 + c15] = acc[r] + bpv;
        }

        mv = mv_n;
        evv = ev_n;
    }
}

extern "C" void kernel_launch(void* const* d_in, const int* in_sizes, int n_in,
                              void* d_out, int out_size, void* d_ws, size_t ws_size,
                              hipStream_t stream) {
    const float* x     = (const float*)d_in[0];
    const int*   amask = (const int*)  d_in[1];
    const float* edge  = (const float*)d_in[2];
    const float* Wqkv  = (const float*)d_in[3];
    const float* bqkv  = (const float*)d_in[4];
    const float* Wproj = (const float*)d_in[5];
    const float* bproj = (const float*)d_in[6];
    const float* eg_w1 = (const float*)d_in[7];
    const float* eg_b1 = (const float*)d_in[8];
    const float* eg_w2 = (const float*)d_in[9];
    const float* eg_b2 = (const float*)d_in[10];
    const float* Wbr   = (const float*)d_in[11];
    const float* bbr   = (const float*)d_in[12];
    float* outp = (float*)d_out;

    unsigned short* Wbig = (unsigned short*)d_ws;                      // 400*128 bf16
    unsigned short* Wp   = (unsigned short*)((char*)d_ws + 400 * 128 * 2);

    hipLaunchKernelGGL(prep_kernel, dim3(264), dim3(256), 0, stream,
                       Wqkv, Wbr, Wproj, Wbig, Wp);
    hipLaunchKernelGGL(leaf_main, dim3(8192 / NITER), dim3(512), 0, stream,
                       x, amask, edge, Wbig, Wp, bqkv, bproj,
                       eg_w1, eg_b1, eg_w2, eg_b2, bbr, outp);
}

// Round 16
// 85.434 us; speedup vs baseline: 2.4385x; 1.1250x over previous
//
#include <hip/hip_runtime.h>
#include <hip/hip_bf16.h>
#include <math.h>

// B=4, NB=2048 -> 8192 leaf blocks of L=16 tokens x C=128; H=8 heads x D=16.
// 512 threads (8 waves), NITER=8 blocks/WG (grid 1024), 2 barriers/iter.
// q/k via SWAPPED-operand MFMA; q/k/v/P register-resident (r14).
// Bq/Bk/Bv/Wt register-resident per WG (r15).
// NEW (r16): edge-gate MLP on the MATRIX cores: per q-row tile,
//   hT = MFMA16(W1-as-A, bpT-as-B); ew^T = MFMA16(W2-as-A, gelu(hT));
// mask row-sum via one ballot per tile (tile == q-row). MLP LDS tables gone.
typedef __attribute__((ext_vector_type(8))) short bf16x8;
typedef __attribute__((ext_vector_type(4))) short bf16x4;
typedef __attribute__((ext_vector_type(4))) float f32x4;
typedef __attribute__((ext_vector_type(4))) unsigned short us4;

#define NITER 8

static __device__ __forceinline__ unsigned short f2bf_rn(float f) {
    union { __hip_bfloat16 h; unsigned short u; } cv;
    cv.h = __float2bfloat16(f);
    return cv.u;
}
static __device__ __forceinline__ float bf2f(unsigned short u) {
    union { unsigned int i; float f; } cv;
    cv.i = ((unsigned int)u) << 16;
    return cv.f;
}
static __device__ __forceinline__ f32x4 MFMA(bf16x8 a, bf16x8 b, f32x4 c) {
    return __builtin_amdgcn_mfma_f32_16x16x32_bf16(a, b, c, 0, 0, 0);
}
static __device__ __forceinline__ f32x4 MFMA16(bf16x4 a, bf16x4 b, f32x4 c) {
#if __has_builtin(__builtin_amdgcn_mfma_f32_16x16x16bf16_1k)
    return __builtin_amdgcn_mfma_f32_16x16x16bf16_1k(a, b, c, 0, 0, 0);
#elif __has_builtin(__builtin_amdgcn_mfma_f32_16x16x16_bf16)
    return __builtin_amdgcn_mfma_f32_16x16x16_bf16(a, b, c, 0, 0, 0);
#else
    f32x4 d;
    asm("v_mfma_f32_16x16x16_bf16 %0, %1, %2, %3"
        : "=v"(d) : "v"(a), "v"(b), "v"(c));
    return d;
#endif
}
static __device__ __forceinline__ float sigmoid_fast(float t) {
    return __builtin_amdgcn_rcpf(1.f + __expf(-t));
}

// ---- prep: Wbig = bf16([Wqkv(384); Wbr(8); zeros(8)]) [400][128]; Wp = bf16(Wproj)
__global__ __launch_bounds__(256) void prep_kernel(
    const float* __restrict__ Wqkv, const float* __restrict__ Wbr,
    const float* __restrict__ Wproj,
    unsigned short* __restrict__ Wbig, unsigned short* __restrict__ Wp)
{
    int i = blockIdx.x * 256 + threadIdx.x;
    if (i < 400 * 128) {
        int n = i >> 7, k = i & 127;
        float v = (n < 384) ? Wqkv[i] : (n < 392 ? Wbr[(n - 384) * 128 + k] : 0.f);
        Wbig[i] = f2bf_rn(v);
    } else {
        int j = i - 400 * 128;
        if (j < 128 * 128) Wp[j] = f2bf_rn(Wproj[j]);
    }
}

__global__ __launch_bounds__(512) void leaf_main(
    const float* __restrict__ x, const int* __restrict__ mask,
    const float* __restrict__ edge,
    const unsigned short* __restrict__ Wbig, const unsigned short* __restrict__ Wp,
    const float* __restrict__ bqkv, const float* __restrict__ bproj,
    const float* __restrict__ eg_w1, const float* __restrict__ eg_b1,
    const float* __restrict__ eg_w2, const float* __restrict__ eg_b2,
    const float* __restrict__ bbr, float* __restrict__ out)
{
    __shared__ unsigned short xS[16 * 128];      // x stage (bf16, swizzled)
    __shared__ unsigned short mhiS[16 * 136];    // x_mid rounded bf16
    __shared__ unsigned short ewS[8 * 256];      // [h][q*16+k]
    __shared__ float logitS[256];                // [q*16+k]
    // total ~14.3 KB

    const int tid  = threadIdx.x;
    const int lane = tid & 63;
    const int wave = tid >> 6;
    const int c15  = lane & 15;
    const int quad = lane >> 4;
    const int bid0 = blockIdx.x * NITER;
    const int t0 = wave * 2, t1 = wave * 2 + 1;   // this wave's q-row tiles

    // iteration-invariant scalars (q/k biases are per-d = quad*4+r based)
    const f32x4 bqv = *(const f32x4*)&bqkv[wave * 16 + quad * 4];
    const f32x4 bkv = *(const f32x4*)&bqkv[128 + wave * 16 + quad * 4];
    const float bq2 = bqkv[256 + wave * 16 + c15];
    const float bgate = bbr[c15 & 7];
    const float bpv = bproj[wave * 16 + c15];

    // ---- resident MLP fragments (uniform) ----
    bf16x4 W1a = {0, 0, 0, 0};    // A[row=j=c15][k=quad*4+r] (k<4 valid)
    if (quad == 0) {
        const f32x4 w1 = *(const f32x4*)&eg_w1[c15 * 4];
        #pragma unroll
        for (int r = 0; r < 4; ++r) W1a[r] = (short)f2bf_rn(w1[r]);
    }
    bf16x4 W2a = {0, 0, 0, 0};    // A[row=h=c15][k=j=quad*4+r] (h<8 valid)
    if (c15 < 8) {
        const f32x4 w2 = *(const f32x4*)&eg_w2[c15 * 16 + quad * 4];
        #pragma unroll
        for (int r = 0; r < 4; ++r) W2a[r] = (short)f2bf_rn(w2[r]);
    }
    const f32x4 b1v = *(const f32x4*)&eg_b1[quad * 4];
    f32x4 b2v = {0.f, 0.f, 0.f, 0.f};
    if (quad < 2) b2v = *(const f32x4*)&eg_b2[quad * 4];

    // ---- REGISTER-RESIDENT weight tiles (once per WG; natural allocation) ----
    const unsigned short* wbase = Wbig + c15 * 128 + quad * 8;
    bf16x8 Bq[4], Bk[4], Bv[4], Wt[4];
    {
        const unsigned short* wq = wbase + (wave * 16) * 128;
        const unsigned short* wk = wbase + ((8 + wave) * 16) * 128;
        const unsigned short* wv = wbase + ((16 + wave) * 16) * 128;
        const unsigned short* wp = Wp + (wave * 16 + c15) * 128 + quad * 8;
        #pragma unroll
        for (int kk = 0; kk < 4; ++kk) {
            Bq[kk] = *(const bf16x8*)(wq + kk * 32);
            Bk[kk] = *(const bf16x8*)(wk + kk * 32);
            Bv[kk] = *(const bf16x8*)(wv + kk * 32);
            Wt[kk] = *(const bf16x8*)(wp + kk * 32);
        }
    }
    const unsigned short* wg = wbase + 384 * 128;   // gate tile (per-iter load)

    // prologue: block 0 inputs (mask/edge on quad-0 lanes only)
    int mvA = 0, mvB = 0;
    float4 evA = make_float4(0.f, 0.f, 0.f, 0.f);
    float4 evB = make_float4(0.f, 0.f, 0.f, 0.f);
    if (quad == 0) {
        const size_t base = (size_t)bid0 * 256;
        mvA = mask[base + t0 * 16 + c15];
        mvB = mask[base + t1 * 16 + c15];
        evA = *(const float4*)&edge[(base + t0 * 16 + c15) * 4];
        evB = *(const float4*)&edge[(base + t1 * 16 + c15) * 4];
    }
    float4 xv = ((const float4*)(x + (size_t)bid0 * 2048))[tid];
    {
        int row = tid >> 5, c4 = tid & 31;
        int off = row * 128 + (((c4 >> 1) ^ (row & 7)) << 3) + ((c4 & 1) << 2);
        us4 hi;
        hi[0] = f2bf_rn(xv.x); hi[1] = f2bf_rn(xv.y);
        hi[2] = f2bf_rn(xv.z); hi[3] = f2bf_rn(xv.w);
        *(us4*)&xS[off] = hi;
    }
    __syncthreads();   // prologue barrier: x0 staged

    #pragma unroll 1
    for (int it = 0; it < NITER; ++it) {
        const int bid = bid0 + it;
        const bool more = (it + 1 < NITER);

        // gate tile load (issued at top; consumed ~1.5k cycles later)
        bf16x8 Bg[4];
        #pragma unroll
        for (int kk = 0; kk < 4; ++kk) Bg[kk] = *(const bf16x8*)(wg + kk * 32);

        // next-block loads (retire under this iteration's compute)
        float4 xv_n = make_float4(0.f, 0.f, 0.f, 0.f);
        int mvA_n = 0, mvB_n = 0;
        float4 evA_n = make_float4(0.f, 0.f, 0.f, 0.f);
        float4 evB_n = make_float4(0.f, 0.f, 0.f, 0.f);
        if (more) {
            xv_n = ((const float4*)(x + (size_t)(bid + 1) * 2048))[tid];
            if (quad == 0) {
                const size_t base = (size_t)(bid + 1) * 256;
                mvA_n = mask[base + t0 * 16 + c15];
                mvB_n = mask[base + t1 * 16 + c15];
                evA_n = *(const float4*)&edge[(base + t0 * 16 + c15) * 4];
                evB_n = *(const float4*)&edge[(base + t1 * 16 + c15) * 4];
            }
        }

        // ---- edge-gate MLP on matrix cores: two q-row tiles per wave ----
        #pragma unroll
        for (int tt = 0; tt < 2; ++tt) {
            const int t = tt ? t1 : t0;
            const int mvt = tt ? mvB : mvA;
            const float4 evt = tt ? evB : evA;
            // layer-1 B fragment: B[k=quad*4+r][col=pair_in_row=c15]
            bf16x4 bpB = {0, 0, 0, 0};
            float bp3 = 0.f;
            if (quad == 0) {
                const bool diag = (c15 == t);
                bp3 = diag ? 1.f : evt.w;
                bpB[0] = (short)f2bf_rn(diag ? 0.f : evt.x);
                bpB[1] = (short)f2bf_rn(diag ? 0.f : evt.y);
                bpB[2] = (short)f2bf_rn(diag ? 0.f : evt.z);
                bpB[3] = (short)f2bf_rn(bp3);
            }
            // mask row (tile == q-row): one ballot, uniform result
            const unsigned long long bl = __ballot(quad == 0 && mvt != 0);
            const unsigned m16 = (unsigned)(bl & 0xFFFFull);
            const bool meff = ((m16 >> c15) & 1u) || (m16 == 0u && c15 == t);
            if (quad == 0)
                logitS[t * 16 + c15] = meff ? bp3 : -INFINITY;
            // hT[j=quad*4+r][pair=c15] = W1 @ bpT  (+b1, gelu)
            f32x4 h1 = {0.f, 0.f, 0.f, 0.f};
            h1 = MFMA16(W1a, bpB, h1);
            bf16x4 hB;
            #pragma unroll
            for (int r = 0; r < 4; ++r) {
                float z = h1[r] + b1v[r];
                float u = z * z;
                float w = __builtin_fmaf(-0.0664904f, u, 0.3989423f);
                float g = z * __builtin_fmaf(z, w, 0.5f);
                hB[r] = (short)f2bf_rn(g);
            }
            // ewT[h=quad*4+r][pair=c15] = W2 @ hT (+b2)
            f32x4 e2 = {0.f, 0.f, 0.f, 0.f};
            e2 = MFMA16(W2a, hB, e2);
            if (quad < 2) {
                #pragma unroll
                for (int r = 0; r < 4; ++r) {
                    float ewv = e2[r] + b2v[r];
                    ewS[(quad * 4 + r) * 256 + t * 16 + c15] =
                        meff ? (unsigned short)(__float_as_uint(ewv) >> 16)
                             : (unsigned short)0;
                }
            }
        }

        // ---- x fragments from xS (serve as A or B operand) ----
        bf16x8 ah[4];
        #pragma unroll
        for (int kk = 0; kk < 4; ++kk) {
            int off = c15 * 128 + (((kk * 4 + quad) ^ (c15 & 7)) << 3);
            ah[kk] = *(const bf16x8*)&xS[off];
        }

        bf16x4 qa, ka, va;
        float vblk;
        float greg[4];

        // ---- tile q: SWAPPED (W as A, x as B) -> Q[tok=c15][d=quad*4+r] ----
        {
            f32x4 acc = {0.f, 0.f, 0.f, 0.f};
            #pragma unroll
            for (int kk = 0; kk < 4; ++kk) acc = MFMA(Bq[kk], ah[kk], acc);
            #pragma unroll
            for (int r = 0; r < 4; ++r) qa[r] = (short)f2bf_rn(acc[r] + bqv[r]);
        }

        // ---- tile k: SWAPPED -> K[tok=c15][d=quad*4+r] ----
        {
            f32x4 acc = {0.f, 0.f, 0.f, 0.f};
            #pragma unroll
            for (int kk = 0; kk < 4; ++kk) acc = MFMA(Bk[kk], ah[kk], acc);
            #pragma unroll
            for (int r = 0; r < 4; ++r) ka[r] = (short)f2bf_rn(acc[r] + bkv[r]);
        }

        // ---- tile v: normal -> V[tok=quad*4+r][d=c15]; v_blk in-register ----
        {
            f32x4 acc = {0.f, 0.f, 0.f, 0.f};
            #pragma unroll
            for (int kk = 0; kk < 4; ++kk) acc = MFMA(ah[kk], Bv[kk], acc);
            #pragma unroll
            for (int r = 0; r < 4; ++r) va[r] = (short)f2bf_rn(acc[r] + bq2);
            float s = acc[0] + acc[1] + acc[2] + acc[3];
            s += __shfl_xor(s, 16);
            s += __shfl_xor(s, 32);
            vblk = s * 0.0625f + bq2;     // v_blk[d=c15] of head `wave`
        }

        // ---- tile gate: normal; keep own column via shuffle ----
        {
            f32x4 acc = {0.f, 0.f, 0.f, 0.f};
            #pragma unroll
            for (int kk = 0; kk < 4; ++kk) acc = MFMA(ah[kk], Bg[kk], acc);
            const int src = (lane & 48) | wave;
            #pragma unroll
            for (int r = 0; r < 4; ++r) {
                float sg = sigmoid_fast(acc[r] + bgate);
                greg[r] = __shfl(sg, src);        // g[tok=quad*4+r][h=wave]
            }
        }
        __syncthreads();   // barrier B: ewS/logitS visible; xS reads done

        // stage NEXT block's x (overlaps attention; visibility via barrier C)
        if (more) {
            int row = tid >> 5, c4 = tid & 31;
            int off = row * 128 + (((c4 >> 1) ^ (row & 7)) << 3) + ((c4 & 1) << 2);
            us4 hi;
            hi[0] = f2bf_rn(xv_n.x); hi[1] = f2bf_rn(xv_n.y);
            hi[2] = f2bf_rn(xv_n.z); hi[3] = f2bf_rn(xv_n.w);
            *(us4*)&xS[off] = hi;
        }

        // ---- attention (head h = wave), fully in-register ----
        {
            f32x4 sc = {0.f, 0.f, 0.f, 0.f};
            sc = MFMA16(ka, qa, sc);          // D[k=quad*4+r][q=c15]
            const f32x4 lg = *(const f32x4*)&logitS[c15 * 16 + quad * 4];
            const us4 ew4 = *(const us4*)&ewS[wave * 256 + c15 * 16 + quad * 4];
            // max-free softmax (|s| <~ 15, f32 exp safe; -inf -> 0)
            float e0 = __expf(__builtin_fmaf(sc[0], 0.25f, lg[0]));
            float e1 = __expf(__builtin_fmaf(sc[1], 0.25f, lg[1]));
            float e2 = __expf(__builtin_fmaf(sc[2], 0.25f, lg[2]));
            float e3 = __expf(__builtin_fmaf(sc[3], 0.25f, lg[3]));
            float sm = (e0 + e1) + (e2 + e3);
            sm += __shfl_xor(sm, 16);
            sm += __shfl_xor(sm, 32);
            const float inv = __builtin_amdgcn_rcpf(sm);
            bf16x4 pa;   // P fragment == scores D layout (same lane, same elems)
            pa[0] = (short)f2bf_rn(__builtin_fmaf(e0, inv, bf2f(ew4[0])));
            pa[1] = (short)f2bf_rn(__builtin_fmaf(e1, inv, bf2f(ew4[1])));
            pa[2] = (short)f2bf_rn(__builtin_fmaf(e2, inv, bf2f(ew4[2])));
            pa[3] = (short)f2bf_rn(__builtin_fmaf(e3, inv, bf2f(ew4[3])));
            f32x4 xs = {0.f, 0.f, 0.f, 0.f};
            xs = MFMA16(pa, va, xs);          // D[q=quad*4+r][d=c15]
            #pragma unroll
            for (int r = 0; r < 4; ++r) {
                const int tok = quad * 4 + r;
                float val = xs[r] + greg[r] * vblk;
                mhiS[tok * 136 + wave * 16 + c15] = f2bf_rn(val);
            }
        }
        __syncthreads();   // barrier C: x_mid + next-x staged visible

        // ---- output projection (resident Wt) ----
        {
            bf16x8 mh[4];
            #pragma unroll
            for (int kk = 0; kk < 4; ++kk)
                mh[kk] = *(const bf16x8*)&mhiS[c15 * 136 + kk * 32 + quad * 8];
            f32x4 acc = {0.f, 0.f, 0.f, 0.f};
            #pragma unroll
            for (int kk = 0; kk < 4; ++kk) acc = MFMA(mh[kk], Wt[kk], acc);
            float* op = out + (size_t)bid * 2048;
            #pragma unroll
            for (int r = 0; r < 4; ++r)
                op[(quad * 4 + r) * 128 + wave * 16 + c15] = acc[r] + bpv;
        }

        mvA = mvA_n; mvB = mvB_n;
        evA = evA_n; evB = evB_n;
    }
}

extern "C" void kernel_launch(void* const* d_in, const int* in_sizes, int n_in,
                              void* d_out, int out_size, void* d_ws, size_t ws_size,
                              hipStream_t stream) {
    const float* x     = (const float*)d_in[0];
    const int*   amask = (const int*)  d_in[1];
    const float* edge  = (const float*)d_in[2];
    const float* Wqkv  = (const float*)d_in[3];
    const float* bqkv  = (const float*)d_in[4];
    const float* Wproj = (const float*)d_in[5];
    const float* bproj = (const float*)d_in[6];
    const float* eg_w1 = (const float*)d_in[7];
    const float* eg_b1 = (const float*)d_in[8];
    const float* eg_w2 = (const float*)d_in[9];
    const float* eg_b2 = (const float*)d_in[10];
    const float* Wbr   = (const float*)d_in[11];
    const float* bbr   = (const float*)d_in[12];
    float* outp = (float*)d_out;

    unsigned short* Wbig = (unsigned short*)d_ws;                      // 400*128 bf16
    unsigned short* Wp   = (unsigned short*)((char*)d_ws + 400 * 128 * 2);

    hipLaunchKernelGGL(prep_kernel, dim3(264), dim3(256), 0, stream,
                       Wqkv, Wbr, Wproj, Wbig, Wp);
    hipLaunchKernelGGL(leaf_main, dim3(8192 / NITER), dim3(512), 0, stream,
                       x, amask, edge, Wbig, Wp, bqkv, bproj,
                       eg_w1, eg_b1, eg_w2, eg_b2, bbr, outp);
}